// Round 11
// baseline (368.869 us; speedup 1.0000x reference)
//
#include <hip/hip_runtime.h>

// B=2, N=96, D=64, H=4, DK=16
#define TENS   1179648   // floats per projected tensor (18432*64)
#define HM     147456    // floats per (b,h) head-major plane (9216*16)
#define T_ROWS 18432
#define NP_S   6         // a-split partial count (chunks of 16 a)
#define NBLK   432       // grid size; co-resident (2 blocks/CU cap >= 512)

// ---------------------------------------------------------------------------
// Software grid barrier (device-scope). All blocks co-resident by capacity:
// LDS 52.5 KB + launch_bounds(256,2) -> 2 blocks/CU, 432 <= 512.
// Release: every thread fences (drains its stores, wb L2), syncthreads,
// thread0 arrives + spins on a device-scope atomic read; acquire: fence all.
// ---------------------------------------------------------------------------
__device__ __forceinline__ void grid_barrier(unsigned* __restrict__ bar, int slot)
{
    __threadfence();                         // release: own stores -> device
    __syncthreads();                         // all waves of block fenced
    if (threadIdx.x == 0) {
        atomicAdd(&bar[slot], 1u);
        while (atomicAdd(&bar[slot], 0u) < (unsigned)NBLK) {
            __builtin_amdgcn_s_sleep(2);
        }
    }
    __syncthreads();
    __threadfence();                         // acquire: invalidate caches
}

// ---------------------------------------------------------------------------
// Megakernel: phase A proj4 -> barrier -> phase B fused attention -> barrier
// -> phase C gather + output projection. Phase math verbatim R10 (verified).
// Shared: union buffer, 13120 floats = 52.5 KB.
// ---------------------------------------------------------------------------
__global__ __launch_bounds__(256, 2) void mega_kernel(
    const float* __restrict__ state,
    const float* __restrict__ w0, const float* __restrict__ b0,
    const float* __restrict__ w1, const float* __restrict__ b1,
    const float* __restrict__ w2, const float* __restrict__ b2,
    const float* __restrict__ w3, const float* __restrict__ b3,
    const float* __restrict__ w4, const float* __restrict__ b4,
    float* __restrict__ lk, float* __restrict__ rk,
    float* __restrict__ lv, float* __restrict__ rv,
    float* __restrict__ nump, float* __restrict__ denp,
    unsigned* __restrict__ bar,
    float* __restrict__ out)
{
    __shared__ float smem[13120];
    const int t   = threadIdx.x;
    const int bid = blockIdx.x;

    // ================= Phase A: 4-way projection (576 jobs) ===============
    {
        float* swt  = smem;           // 64*68 transposed W
        float* srow = smem + 4352;    // 128*68
        float* sb   = smem + 13056;   // 64
        for (int job = bid; job < 576; job += NBLK) {
            const int mat = job & 3;
            const int g   = job >> 2;            // 0..143
            const int row0 = g * 128;            // never straddles a batch
            const float* w  = (mat == 0) ? w0 : (mat == 1) ? w1 : (mat == 2) ? w2 : w3;
            const float* bi = (mat == 0) ? b0 : (mat == 1) ? b1 : (mat == 2) ? b2 : b3;
            float* o        = (mat == 0) ? lk : (mat == 1) ? rk : (mat == 2) ? lv : rv;

            __syncthreads();                     // protect LDS across jobs
#pragma unroll
            for (int j = 0; j < 4; ++j) {        // stage W transposed
                const int s = t + j * 256;
                const int c = s >> 4, k4 = s & 15;
                const float4 wv = *(const float4*)(w + c * 64 + k4 * 4);
                swt[(k4 * 4 + 0) * 68 + c] = wv.x;
                swt[(k4 * 4 + 1) * 68 + c] = wv.y;
                swt[(k4 * 4 + 2) * 68 + c] = wv.z;
                swt[(k4 * 4 + 3) * 68 + c] = wv.w;
            }
#pragma unroll
            for (int j = 0; j < 8; ++j) {        // stage 128 src rows
                const int s = t + j * 256;
                const int row = s >> 4, k4 = s & 15;
                *(float4*)&srow[row * 68 + k4 * 4] =
                    *(const float4*)(state + (size_t)(row0 + row) * 64 + k4 * 4);
            }
            if (t < 64) sb[t] = bi[t];
            __syncthreads();

            const int c4 = t & 15, rg = t >> 4;
            const float4 binit = *(const float4*)&sb[c4 * 4];
            float4 acc[8];
#pragma unroll
            for (int rr = 0; rr < 8; ++rr) acc[rr] = binit;
#pragma unroll
            for (int k4 = 0; k4 < 16; ++k4) {
                const float4 wq0 = *(const float4*)&swt[(k4 * 4 + 0) * 68 + c4 * 4];
                const float4 wq1 = *(const float4*)&swt[(k4 * 4 + 1) * 68 + c4 * 4];
                const float4 wq2 = *(const float4*)&swt[(k4 * 4 + 2) * 68 + c4 * 4];
                const float4 wq3 = *(const float4*)&swt[(k4 * 4 + 3) * 68 + c4 * 4];
#pragma unroll
                for (int rr = 0; rr < 8; ++rr) {
                    const float4 s4 = *(const float4*)&srow[(rg + rr * 16) * 68 + k4 * 4];
                    acc[rr].x = fmaf(s4.x, wq0.x, acc[rr].x);
                    acc[rr].y = fmaf(s4.x, wq0.y, acc[rr].y);
                    acc[rr].z = fmaf(s4.x, wq0.z, acc[rr].z);
                    acc[rr].w = fmaf(s4.x, wq0.w, acc[rr].w);
                    acc[rr].x = fmaf(s4.y, wq1.x, acc[rr].x);
                    acc[rr].y = fmaf(s4.y, wq1.y, acc[rr].y);
                    acc[rr].z = fmaf(s4.y, wq1.z, acc[rr].z);
                    acc[rr].w = fmaf(s4.y, wq1.w, acc[rr].w);
                    acc[rr].x = fmaf(s4.z, wq2.x, acc[rr].x);
                    acc[rr].y = fmaf(s4.z, wq2.y, acc[rr].y);
                    acc[rr].z = fmaf(s4.z, wq2.z, acc[rr].z);
                    acc[rr].w = fmaf(s4.z, wq2.w, acc[rr].w);
                    acc[rr].x = fmaf(s4.w, wq3.x, acc[rr].x);
                    acc[rr].y = fmaf(s4.w, wq3.y, acc[rr].y);
                    acc[rr].z = fmaf(s4.w, wq3.z, acc[rr].z);
                    acc[rr].w = fmaf(s4.w, wq3.w, acc[rr].w);
                }
            }
            const int b  = row0 / 9216;
            const int h  = c4 >> 2;
            const int dq = c4 & 3;
            float* dp = o + (size_t)(b * 4 + h) * HM + dq * 4;
            const int rb0 = row0 - b * 9216 + rg;
#pragma unroll
            for (int rr = 0; rr < 8; ++rr)
                *(float4*)(dp + (size_t)(rb0 + rr * 16) * 16) = acc[rr];
        }
    }
    grid_barrier(bar, 0);

    // ========= Phase B: fused attention (432 jobs, 1 per block) ===========
    {
        float* lk_s = smem;           // 32 x-slots * pitch 68
        float* lv_s = smem + 2176;
        float* rk_s = smem + 4352;    // 4 ai * (32 y-slots * pitch 20)
        float* rv_s = smem + 6912;
        const int jb = bid;
        const int bh = jb & 7;
        const int r2 = jb >> 3;
        const int sc = r2 % 6;
        const int tile = r2 / 6;
        const int xt = tile % 3, yt = tile / 3;
        const int x0 = xt * 32, y0 = yt * 32;
        const int a00 = sc * 16;
        const int xi2 = t & 15, yi2 = t >> 4;

        const float* plk = lk + (size_t)bh * HM;
        const float* prk = rk + (size_t)bh * HM;
        const float* plv = lv + (size_t)bh * HM;
        const float* prv = rv + (size_t)bh * HM;

        float4 a00v = {0.f,0.f,0.f,0.f}, a01v = a00v, a02v = a00v, a03v = a00v;
        float4 a10v = a00v, a11v = a00v, a12v = a00v, a13v = a00v;
        float4 a20v = a00v, a21v = a00v, a22v = a00v, a23v = a00v;
        float4 a30v = a00v, a31v = a00v, a32v = a00v, a33v = a00v;
        float d00 = 0.f, d01 = 0.f, d10 = 0.f, d11 = 0.f;

        for (int acx = 0; acx < 4; ++acx) {
            const int a0 = a00 + acx * 4;
            __syncthreads();
#pragma unroll
            for (int jj = 0; jj < 2; ++jj) {
                const int slot = t + jj * 256;
                const int xl = slot >> 4, rem = slot & 15;
                const int ai = rem >> 2, c4 = rem & 3;
                const int goff = ((x0 + xl) * 96 + a0 + ai) * 16 + c4 * 4;
                const int loff = ((xl & 1) * 16 + (xl >> 1)) * 68 + ai * 16 + c4 * 4;
                *(float4*)&lk_s[loff] = *(const float4*)(plk + goff);
                *(float4*)&lv_s[loff] = *(const float4*)(plv + goff);
            }
#pragma unroll
            for (int jj = 0; jj < 2; ++jj) {
                const int slot = t + jj * 256;
                const int ai = slot >> 7, rem = slot & 127;
                const int yl = rem >> 2, c4 = rem & 3;
                const int goff = ((a0 + ai) * 96 + y0 + yl) * 16 + c4 * 4;
                const int loff = ai * 640 + ((yl & 1) * 16 + (yl >> 1)) * 20 + c4 * 4;
                *(float4*)&rk_s[loff] = *(const float4*)(prk + goff);
                *(float4*)&rv_s[loff] = *(const float4*)(prv + goff);
            }
            __syncthreads();
#pragma unroll
            for (int ai = 0; ai < 4; ++ai) {
                const int lo0 = xi2 * 68 + ai * 16;
                const int lo1 = (16 + xi2) * 68 + ai * 16;
                const int ro0 = ai * 640 + yi2 * 20;
                const int ro1 = ai * 640 + (16 + yi2) * 20;
                const float4 ka0 = *(const float4*)&lk_s[lo0];
                const float4 ka1 = *(const float4*)&lk_s[lo0 + 4];
                const float4 ka2 = *(const float4*)&lk_s[lo0 + 8];
                const float4 ka3 = *(const float4*)&lk_s[lo0 + 12];
                const float4 kb0 = *(const float4*)&lk_s[lo1];
                const float4 kb1 = *(const float4*)&lk_s[lo1 + 4];
                const float4 kb2 = *(const float4*)&lk_s[lo1 + 8];
                const float4 kb3 = *(const float4*)&lk_s[lo1 + 12];
                const float4 qa0 = *(const float4*)&rk_s[ro0];
                const float4 qa1 = *(const float4*)&rk_s[ro0 + 4];
                const float4 qa2 = *(const float4*)&rk_s[ro0 + 8];
                const float4 qa3 = *(const float4*)&rk_s[ro0 + 12];
                const float4 qb0 = *(const float4*)&rk_s[ro1];
                const float4 qb1 = *(const float4*)&rk_s[ro1 + 4];
                const float4 qb2 = *(const float4*)&rk_s[ro1 + 8];
                const float4 qb3 = *(const float4*)&rk_s[ro1 + 12];

#define DOT16(A0,A1,A2,A3,B0,B1,B2,B3)                                   \
    fmaf(A3.w,B3.w, fmaf(A3.z,B3.z, fmaf(A3.y,B3.y, fmaf(A3.x,B3.x,     \
    fmaf(A2.w,B2.w, fmaf(A2.z,B2.z, fmaf(A2.y,B2.y, fmaf(A2.x,B2.x,     \
    fmaf(A1.w,B1.w, fmaf(A1.z,B1.z, fmaf(A1.y,B1.y, fmaf(A1.x,B1.x,     \
    fmaf(A0.w,B0.w, fmaf(A0.z,B0.z, fmaf(A0.y,B0.y, A0.x*B0.x)))))))))))))))
                const float s00 = DOT16(ka0,ka1,ka2,ka3, qa0,qa1,qa2,qa3);
                const float s01 = DOT16(ka0,ka1,ka2,ka3, qb0,qb1,qb2,qb3);
                const float s10 = DOT16(kb0,kb1,kb2,kb3, qa0,qa1,qa2,qa3);
                const float s11 = DOT16(kb0,kb1,kb2,kb3, qb0,qb1,qb2,qb3);
#undef DOT16
                const float p00 = __expf(s00 * 0.25f);   // 1/sqrt(16); |s| << 1
                const float p01 = __expf(s01 * 0.25f);
                const float p10 = __expf(s10 * 0.25f);
                const float p11 = __expf(s11 * 0.25f);
                d00 += p00; d01 += p01; d10 += p10; d11 += p11;

                const float4 la0 = *(const float4*)&lv_s[lo0];
                const float4 la1 = *(const float4*)&lv_s[lo0 + 4];
                const float4 la2 = *(const float4*)&lv_s[lo0 + 8];
                const float4 la3 = *(const float4*)&lv_s[lo0 + 12];
                const float4 lb0 = *(const float4*)&lv_s[lo1];
                const float4 lb1 = *(const float4*)&lv_s[lo1 + 4];
                const float4 lb2 = *(const float4*)&lv_s[lo1 + 8];
                const float4 lb3 = *(const float4*)&lv_s[lo1 + 12];
                const float4 va0 = *(const float4*)&rv_s[ro0];
                const float4 va1 = *(const float4*)&rv_s[ro0 + 4];
                const float4 va2 = *(const float4*)&rv_s[ro0 + 8];
                const float4 va3 = *(const float4*)&rv_s[ro0 + 12];
                const float4 vb0 = *(const float4*)&rv_s[ro1];
                const float4 vb1 = *(const float4*)&rv_s[ro1 + 4];
                const float4 vb2 = *(const float4*)&rv_s[ro1 + 8];
                const float4 vb3 = *(const float4*)&rv_s[ro1 + 12];

#define ACC4(AC, P, L, V)                       \
    AC.x = fmaf(P * L.x, V.x, AC.x);            \
    AC.y = fmaf(P * L.y, V.y, AC.y);            \
    AC.z = fmaf(P * L.z, V.z, AC.z);            \
    AC.w = fmaf(P * L.w, V.w, AC.w);
                ACC4(a00v, p00, la0, va0) ACC4(a01v, p00, la1, va1)
                ACC4(a02v, p00, la2, va2) ACC4(a03v, p00, la3, va3)
                ACC4(a10v, p01, la0, vb0) ACC4(a11v, p01, la1, vb1)
                ACC4(a12v, p01, la2, vb2) ACC4(a13v, p01, la3, vb3)
                ACC4(a20v, p10, lb0, va0) ACC4(a21v, p10, lb1, va1)
                ACC4(a22v, p10, lb2, va2) ACC4(a23v, p10, lb3, va3)
                ACC4(a30v, p11, lb0, vb0) ACC4(a31v, p11, lb1, vb1)
                ACC4(a32v, p11, lb2, vb2) ACC4(a33v, p11, lb3, vb3)
#undef ACC4
            }
        }

        const size_t pb = (size_t)(sc * 8 + bh) * 9216;
        const int xA = x0 + 2 * xi2, yA = y0 + 2 * yi2;
        {
            const size_t rb = pb + (size_t)xA * 96 + yA;
            float4* np = (float4*)(nump + rb * 16);
            np[0] = a00v; np[1] = a01v; np[2] = a02v; np[3] = a03v;
            denp[rb] = d00;
        }
        {
            const size_t rb = pb + (size_t)xA * 96 + yA + 1;
            float4* np = (float4*)(nump + rb * 16);
            np[0] = a10v; np[1] = a11v; np[2] = a12v; np[3] = a13v;
            denp[rb] = d01;
        }
        {
            const size_t rb = pb + (size_t)(xA + 1) * 96 + yA;
            float4* np = (float4*)(nump + rb * 16);
            np[0] = a20v; np[1] = a21v; np[2] = a22v; np[3] = a23v;
            denp[rb] = d10;
        }
        {
            const size_t rb = pb + (size_t)(xA + 1) * 96 + yA + 1;
            float4* np = (float4*)(nump + rb * 16);
            np[0] = a30v; np[1] = a31v; np[2] = a32v; np[3] = a33v;
            denp[rb] = d11;
        }
    }
    grid_barrier(bar, 1);

    // ===== Phase C: partial gather + output projection (144 jobs) =========
    if (bid < 144) {
        float* swt  = smem;
        float* srow = smem + 4352;
        float* sb   = smem + 13056;
        const int row0 = bid * 128;
        const int bb  = row0 / 9216;
        const int rb0 = row0 - bb * 9216;

        __syncthreads();                         // LDS reuse after phase B
#pragma unroll
        for (int j = 0; j < 4; ++j) {            // stage w_out transposed
            const int s = t + j * 256;
            const int c = s >> 4, k4 = s & 15;
            const float4 wv = *(const float4*)(w4 + c * 64 + k4 * 4);
            swt[(k4 * 4 + 0) * 68 + c] = wv.x;
            swt[(k4 * 4 + 1) * 68 + c] = wv.y;
            swt[(k4 * 4 + 2) * 68 + c] = wv.z;
            swt[(k4 * 4 + 3) * 68 + c] = wv.w;
        }
#pragma unroll
        for (int j = 0; j < 8; ++j) {            // gather 128 rows
            const int s = t + j * 256;
            const int rl = s >> 4, hc = s & 15;
            const int bh = bb * 4 + (hc >> 2);
            const int c4g = hc & 3;
            const int rb = rb0 + rl;
            float sx = 0.f, sy = 0.f, sz = 0.f, sw4 = 0.f, dd = 0.f;
#pragma unroll
            for (int sc = 0; sc < NP_S; ++sc) {
                const size_t rbs = (size_t)(sc * 8 + bh) * 9216 + rb;
                const float4 v = *(const float4*)(nump + rbs * 16 + c4g * 4);
                sx += v.x; sy += v.y; sz += v.z; sw4 += v.w;
                dd += denp[rbs];
            }
            const float inv = 1.0f / dd;
            float4 ov; ov.x = sx * inv; ov.y = sy * inv; ov.z = sz * inv; ov.w = sw4 * inv;
            *(float4*)&srow[rl * 68 + hc * 4] = ov;
        }
        if (t < 64) sb[t] = b4[t];
        __syncthreads();

        const int c4 = t & 15, rg = t >> 4;
        const float4 binit = *(const float4*)&sb[c4 * 4];
        float4 acc[8];
#pragma unroll
        for (int rr = 0; rr < 8; ++rr) acc[rr] = binit;
#pragma unroll
        for (int k4 = 0; k4 < 16; ++k4) {
            const float4 wq0 = *(const float4*)&swt[(k4 * 4 + 0) * 68 + c4 * 4];
            const float4 wq1 = *(const float4*)&swt[(k4 * 4 + 1) * 68 + c4 * 4];
            const float4 wq2 = *(const float4*)&swt[(k4 * 4 + 2) * 68 + c4 * 4];
            const float4 wq3 = *(const float4*)&swt[(k4 * 4 + 3) * 68 + c4 * 4];
#pragma unroll
            for (int rr = 0; rr < 8; ++rr) {
                const float4 s4 = *(const float4*)&srow[(rg + rr * 16) * 68 + k4 * 4];
                acc[rr].x = fmaf(s4.x, wq0.x, acc[rr].x);
                acc[rr].y = fmaf(s4.x, wq0.y, acc[rr].y);
                acc[rr].z = fmaf(s4.x, wq0.z, acc[rr].z);
                acc[rr].w = fmaf(s4.x, wq0.w, acc[rr].w);
                acc[rr].x = fmaf(s4.y, wq1.x, acc[rr].x);
                acc[rr].y = fmaf(s4.y, wq1.y, acc[rr].y);
                acc[rr].z = fmaf(s4.y, wq1.z, acc[rr].z);
                acc[rr].w = fmaf(s4.y, wq1.w, acc[rr].w);
                acc[rr].x = fmaf(s4.z, wq2.x, acc[rr].x);
                acc[rr].y = fmaf(s4.z, wq2.y, acc[rr].y);
                acc[rr].z = fmaf(s4.z, wq2.z, acc[rr].z);
                acc[rr].w = fmaf(s4.z, wq2.w, acc[rr].w);
                acc[rr].x = fmaf(s4.w, wq3.x, acc[rr].x);
                acc[rr].y = fmaf(s4.w, wq3.y, acc[rr].y);
                acc[rr].z = fmaf(s4.w, wq3.z, acc[rr].z);
                acc[rr].w = fmaf(s4.w, wq3.w, acc[rr].w);
            }
        }
#pragma unroll
        for (int rr = 0; rr < 8; ++rr)
            *(float4*)(out + (size_t)(row0 + rg + rr * 16) * 64 + c4 * 4) = acc[rr];
    }
}

extern "C" void kernel_launch(void* const* d_in, const int* in_sizes, int n_in,
                              void* d_out, int out_size, void* d_ws, size_t ws_size,
                              hipStream_t stream)
{
    const float* state = (const float*)d_in[0];
    const float* w_lk  = (const float*)d_in[1];
    const float* b_lk  = (const float*)d_in[2];
    const float* w_rk  = (const float*)d_in[3];
    const float* b_rk  = (const float*)d_in[4];
    const float* w_lv  = (const float*)d_in[5];
    const float* b_lv  = (const float*)d_in[6];
    const float* w_rv  = (const float*)d_in[7];
    const float* b_rv  = (const float*)d_in[8];
    const float* w_out = (const float*)d_in[9];
    const float* b_out = (const float*)d_in[10];
    float* out = (float*)d_out;

    float* ws = (float*)d_ws;
    float* lk   = ws;                          // head-major [bh][row][16]
    float* rk   = ws + (size_t)TENS;
    float* lv   = ws + (size_t)2 * TENS;
    float* rv   = ws + (size_t)3 * TENS;
    float* nump = ws + (size_t)4 * TENS;       // 28.3 MB partials
    float* denp = nump + (size_t)NP_S * 8 * 9216 * 16;
    unsigned* bar = (unsigned*)(denp + (size_t)NP_S * 8 * 9216);

    hipMemsetAsync(bar, 0, 2 * sizeof(unsigned), stream);
    mega_kernel<<<NBLK, 256, 0, stream>>>(
        state, w_lk, b_lk, w_rk, b_rk, w_lv, b_lv, w_rv, b_rv, w_out, b_out,
        lk, rk, lv, rv, nump, denp, bar, out);
}

// Round 12
// 134.992 us; speedup vs baseline: 2.7325x; 2.7325x over previous
//
#include <hip/hip_runtime.h>

// B=2, N=96, D=64, H=4, DK=16
#define TENS   1179648   // floats per projected tensor (18432*64)
#define HM     147456    // floats per (b,h) head-major plane (9216*16)
#define T_ROWS 18432
#define NP_S   6         // a-split partial count (chunks of 16 a)

// ---------------------------------------------------------------------------
// proj4 v3: 288 blocks x 64 rows; ALL FOUR matrices per block (state staged
// once, W's sequentially). 8x4-style thread tile: c4 = t&15 (4 cols),
// rg = t>>4, rows rg + rr*16 (rr<4). swt transposed pitch 68 (2-way, free);
// srow pitch 68 (broadcast). Outputs head-major [bh][row][16].
// ---------------------------------------------------------------------------
__global__ __launch_bounds__(256) void proj4_kernel(
    const float* __restrict__ state,
    const float* __restrict__ w0, const float* __restrict__ b0,
    const float* __restrict__ w1, const float* __restrict__ b1,
    const float* __restrict__ w2, const float* __restrict__ b2,
    const float* __restrict__ w3, const float* __restrict__ b3,
    float* __restrict__ o0, float* __restrict__ o1,
    float* __restrict__ o2, float* __restrict__ o3)
{
    __shared__ float swt[64 * 68];    // [k][c] transposed, current mat
    __shared__ float srow[64 * 68];   // [row][k], staged once
    __shared__ float sb[64];
    const int t = threadIdx.x;
    const int row0 = blockIdx.x * 64;      // 9216/64=144: never straddles batch

#pragma unroll
    for (int j = 0; j < 4; ++j) {          // stage 64 src rows once
        const int s = t + j * 256;
        const int row = s >> 4, k4 = s & 15;
        *(float4*)&srow[row * 68 + k4 * 4] =
            *(const float4*)(state + (size_t)(row0 + row) * 64 + k4 * 4);
    }
    const int b   = row0 / 9216;
    const int rb0 = row0 - b * 9216;
    const int c4 = t & 15, rg = t >> 4;
    const int h  = c4 >> 2;
    const int dq = c4 & 3;

    for (int mat = 0; mat < 4; ++mat) {
        const float* w  = (mat == 0) ? w0 : (mat == 1) ? w1 : (mat == 2) ? w2 : w3;
        const float* bi = (mat == 0) ? b0 : (mat == 1) ? b1 : (mat == 2) ? b2 : b3;
        float* o        = (mat == 0) ? o0 : (mat == 1) ? o1 : (mat == 2) ? o2 : o3;

        __syncthreads();                   // protect swt from previous readers
#pragma unroll
        for (int j = 0; j < 4; ++j) {      // stage W transposed
            const int s = t + j * 256;
            const int c = s >> 4, k4 = s & 15;
            const float4 wv = *(const float4*)(w + c * 64 + k4 * 4);
            swt[(k4 * 4 + 0) * 68 + c] = wv.x;
            swt[(k4 * 4 + 1) * 68 + c] = wv.y;
            swt[(k4 * 4 + 2) * 68 + c] = wv.z;
            swt[(k4 * 4 + 3) * 68 + c] = wv.w;
        }
        if (t < 64) sb[t] = bi[t];
        __syncthreads();

        const float4 binit = *(const float4*)&sb[c4 * 4];
        float4 acc[4];
#pragma unroll
        for (int rr = 0; rr < 4; ++rr) acc[rr] = binit;
#pragma unroll
        for (int k4 = 0; k4 < 16; ++k4) {
            const float4 wq0 = *(const float4*)&swt[(k4 * 4 + 0) * 68 + c4 * 4];
            const float4 wq1 = *(const float4*)&swt[(k4 * 4 + 1) * 68 + c4 * 4];
            const float4 wq2 = *(const float4*)&swt[(k4 * 4 + 2) * 68 + c4 * 4];
            const float4 wq3 = *(const float4*)&swt[(k4 * 4 + 3) * 68 + c4 * 4];
#pragma unroll
            for (int rr = 0; rr < 4; ++rr) {
                const float4 s4 = *(const float4*)&srow[(rg + rr * 16) * 68 + k4 * 4];
                acc[rr].x = fmaf(s4.x, wq0.x, acc[rr].x);
                acc[rr].y = fmaf(s4.x, wq0.y, acc[rr].y);
                acc[rr].z = fmaf(s4.x, wq0.z, acc[rr].z);
                acc[rr].w = fmaf(s4.x, wq0.w, acc[rr].w);
                acc[rr].x = fmaf(s4.y, wq1.x, acc[rr].x);
                acc[rr].y = fmaf(s4.y, wq1.y, acc[rr].y);
                acc[rr].z = fmaf(s4.y, wq1.z, acc[rr].z);
                acc[rr].w = fmaf(s4.y, wq1.w, acc[rr].w);
                acc[rr].x = fmaf(s4.z, wq2.x, acc[rr].x);
                acc[rr].y = fmaf(s4.z, wq2.y, acc[rr].y);
                acc[rr].z = fmaf(s4.z, wq2.z, acc[rr].z);
                acc[rr].w = fmaf(s4.z, wq2.w, acc[rr].w);
                acc[rr].x = fmaf(s4.w, wq3.x, acc[rr].x);
                acc[rr].y = fmaf(s4.w, wq3.y, acc[rr].y);
                acc[rr].z = fmaf(s4.w, wq3.z, acc[rr].z);
                acc[rr].w = fmaf(s4.w, wq3.w, acc[rr].w);
            }
        }
        float* dp = o + (size_t)(b * 4 + h) * HM + dq * 4;
#pragma unroll
        for (int rr = 0; rr < 4; ++rr)
            *(float4*)(dp + (size_t)(rb0 + rg + rr * 16) * 16) = acc[rr];
    }
}

// ---------------------------------------------------------------------------
// Fused attention (verbatim R10): 2x2 register blocking + a-split partials.
// 432 blocks x 256 threads; block = (bh, sc a-chunk of 16, 32x32 xy-tile).
// ---------------------------------------------------------------------------
__global__ __launch_bounds__(256) void fused_attn_kernel(
    const float* __restrict__ lk, const float* __restrict__ rk,
    const float* __restrict__ lv, const float* __restrict__ rv,
    float* __restrict__ nump, float* __restrict__ denp)
{
    __shared__ float lk_s[2176];   // 32 x-slots * pitch 68
    __shared__ float lv_s[2176];
    __shared__ float rk_s[2560];   // 4 ai * (32 y-slots * pitch 20)
    __shared__ float rv_s[2560];

    const int t = threadIdx.x;
    const int j = blockIdx.x;            // 0..431
    const int bh = j & 7;
    const int r2 = j >> 3;               // 0..53
    const int sc = r2 % 6;
    const int tile = r2 / 6;             // 0..8
    const int xt = tile % 3, yt = tile / 3;
    const int x0 = xt * 32, y0 = yt * 32;
    const int a00 = sc * 16;
    const int xi2 = t & 15, yi2 = t >> 4;

    const float* plk = lk + (size_t)bh * HM;
    const float* prk = rk + (size_t)bh * HM;
    const float* plv = lv + (size_t)bh * HM;
    const float* prv = rv + (size_t)bh * HM;

    float4 a00v = {0.f,0.f,0.f,0.f}, a01v = a00v, a02v = a00v, a03v = a00v;
    float4 a10v = a00v, a11v = a00v, a12v = a00v, a13v = a00v;
    float4 a20v = a00v, a21v = a00v, a22v = a00v, a23v = a00v;
    float4 a30v = a00v, a31v = a00v, a32v = a00v, a33v = a00v;
    float d00 = 0.f, d01 = 0.f, d10 = 0.f, d11 = 0.f;

    for (int acx = 0; acx < 4; ++acx) {
        const int a0 = a00 + acx * 4;
        __syncthreads();
#pragma unroll
        for (int jj = 0; jj < 2; ++jj) {
            const int slot = t + jj * 256;
            const int xl = slot >> 4, rem = slot & 15;
            const int ai = rem >> 2, c4 = rem & 3;
            const int goff = ((x0 + xl) * 96 + a0 + ai) * 16 + c4 * 4;
            const int loff = ((xl & 1) * 16 + (xl >> 1)) * 68 + ai * 16 + c4 * 4;
            *(float4*)&lk_s[loff] = *(const float4*)(plk + goff);
            *(float4*)&lv_s[loff] = *(const float4*)(plv + goff);
        }
#pragma unroll
        for (int jj = 0; jj < 2; ++jj) {
            const int slot = t + jj * 256;
            const int ai = slot >> 7, rem = slot & 127;
            const int yl = rem >> 2, c4 = rem & 3;
            const int goff = ((a0 + ai) * 96 + y0 + yl) * 16 + c4 * 4;
            const int loff = ai * 640 + ((yl & 1) * 16 + (yl >> 1)) * 20 + c4 * 4;
            *(float4*)&rk_s[loff] = *(const float4*)(prk + goff);
            *(float4*)&rv_s[loff] = *(const float4*)(prv + goff);
        }
        __syncthreads();
#pragma unroll
        for (int ai = 0; ai < 4; ++ai) {
            const int lo0 = xi2 * 68 + ai * 16;
            const int lo1 = (16 + xi2) * 68 + ai * 16;
            const int ro0 = ai * 640 + yi2 * 20;
            const int ro1 = ai * 640 + (16 + yi2) * 20;
            const float4 ka0 = *(const float4*)&lk_s[lo0];
            const float4 ka1 = *(const float4*)&lk_s[lo0 + 4];
            const float4 ka2 = *(const float4*)&lk_s[lo0 + 8];
            const float4 ka3 = *(const float4*)&lk_s[lo0 + 12];
            const float4 kb0 = *(const float4*)&lk_s[lo1];
            const float4 kb1 = *(const float4*)&lk_s[lo1 + 4];
            const float4 kb2 = *(const float4*)&lk_s[lo1 + 8];
            const float4 kb3 = *(const float4*)&lk_s[lo1 + 12];
            const float4 qa0 = *(const float4*)&rk_s[ro0];
            const float4 qa1 = *(const float4*)&rk_s[ro0 + 4];
            const float4 qa2 = *(const float4*)&rk_s[ro0 + 8];
            const float4 qa3 = *(const float4*)&rk_s[ro0 + 12];
            const float4 qb0 = *(const float4*)&rk_s[ro1];
            const float4 qb1 = *(const float4*)&rk_s[ro1 + 4];
            const float4 qb2 = *(const float4*)&rk_s[ro1 + 8];
            const float4 qb3 = *(const float4*)&rk_s[ro1 + 12];

#define DOT16(A0,A1,A2,A3,B0,B1,B2,B3)                                   \
    fmaf(A3.w,B3.w, fmaf(A3.z,B3.z, fmaf(A3.y,B3.y, fmaf(A3.x,B3.x,     \
    fmaf(A2.w,B2.w, fmaf(A2.z,B2.z, fmaf(A2.y,B2.y, fmaf(A2.x,B2.x,     \
    fmaf(A1.w,B1.w, fmaf(A1.z,B1.z, fmaf(A1.y,B1.y, fmaf(A1.x,B1.x,     \
    fmaf(A0.w,B0.w, fmaf(A0.z,B0.z, fmaf(A0.y,B0.y, A0.x*B0.x)))))))))))))))
            const float s00 = DOT16(ka0,ka1,ka2,ka3, qa0,qa1,qa2,qa3);
            const float s01 = DOT16(ka0,ka1,ka2,ka3, qb0,qb1,qb2,qb3);
            const float s10 = DOT16(kb0,kb1,kb2,kb3, qa0,qa1,qa2,qa3);
            const float s11 = DOT16(kb0,kb1,kb2,kb3, qb0,qb1,qb2,qb3);
#undef DOT16
            const float p00 = __expf(s00 * 0.25f);   // 1/sqrt(16); |s| << 1
            const float p01 = __expf(s01 * 0.25f);
            const float p10 = __expf(s10 * 0.25f);
            const float p11 = __expf(s11 * 0.25f);
            d00 += p00; d01 += p01; d10 += p10; d11 += p11;

            const float4 la0 = *(const float4*)&lv_s[lo0];
            const float4 la1 = *(const float4*)&lv_s[lo0 + 4];
            const float4 la2 = *(const float4*)&lv_s[lo0 + 8];
            const float4 la3 = *(const float4*)&lv_s[lo0 + 12];
            const float4 lb0 = *(const float4*)&lv_s[lo1];
            const float4 lb1 = *(const float4*)&lv_s[lo1 + 4];
            const float4 lb2 = *(const float4*)&lv_s[lo1 + 8];
            const float4 lb3 = *(const float4*)&lv_s[lo1 + 12];
            const float4 va0 = *(const float4*)&rv_s[ro0];
            const float4 va1 = *(const float4*)&rv_s[ro0 + 4];
            const float4 va2 = *(const float4*)&rv_s[ro0 + 8];
            const float4 va3 = *(const float4*)&rv_s[ro0 + 12];
            const float4 vb0 = *(const float4*)&rv_s[ro1];
            const float4 vb1 = *(const float4*)&rv_s[ro1 + 4];
            const float4 vb2 = *(const float4*)&rv_s[ro1 + 8];
            const float4 vb3 = *(const float4*)&rv_s[ro1 + 12];

#define ACC4(AC, P, L, V)                       \
    AC.x = fmaf(P * L.x, V.x, AC.x);            \
    AC.y = fmaf(P * L.y, V.y, AC.y);            \
    AC.z = fmaf(P * L.z, V.z, AC.z);            \
    AC.w = fmaf(P * L.w, V.w, AC.w);
            ACC4(a00v, p00, la0, va0) ACC4(a01v, p00, la1, va1)
            ACC4(a02v, p00, la2, va2) ACC4(a03v, p00, la3, va3)
            ACC4(a10v, p01, la0, vb0) ACC4(a11v, p01, la1, vb1)
            ACC4(a12v, p01, la2, vb2) ACC4(a13v, p01, la3, vb3)
            ACC4(a20v, p10, lb0, va0) ACC4(a21v, p10, lb1, va1)
            ACC4(a22v, p10, lb2, va2) ACC4(a23v, p10, lb3, va3)
            ACC4(a30v, p11, lb0, vb0) ACC4(a31v, p11, lb1, vb1)
            ACC4(a32v, p11, lb2, vb2) ACC4(a33v, p11, lb3, vb3)
#undef ACC4
        }
    }

    const size_t pb = (size_t)(sc * 8 + bh) * 9216;
    const int xA = x0 + 2 * xi2, yA = y0 + 2 * yi2;
    {
        const size_t rb = pb + (size_t)xA * 96 + yA;
        float4* np = (float4*)(nump + rb * 16);
        np[0] = a00v; np[1] = a01v; np[2] = a02v; np[3] = a03v;
        denp[rb] = d00;
    }
    {
        const size_t rb = pb + (size_t)xA * 96 + yA + 1;
        float4* np = (float4*)(nump + rb * 16);
        np[0] = a10v; np[1] = a11v; np[2] = a12v; np[3] = a13v;
        denp[rb] = d01;
    }
    {
        const size_t rb = pb + (size_t)(xA + 1) * 96 + yA;
        float4* np = (float4*)(nump + rb * 16);
        np[0] = a20v; np[1] = a21v; np[2] = a22v; np[3] = a23v;
        denp[rb] = d10;
    }
    {
        const size_t rb = pb + (size_t)(xA + 1) * 96 + yA + 1;
        float4* np = (float4*)(nump + rb * 16);
        np[0] = a30v; np[1] = a31v; np[2] = a32v; np[3] = a33v;
        denp[rb] = d11;
    }
}

// ---------------------------------------------------------------------------
// proj1 v3: 288 blocks x 64 rows (was 144x128 -> 44% CU idle). Gather 6
// partials + divide into srow, then 64x64 GEMM (4x4-col thread tile).
// ---------------------------------------------------------------------------
__global__ __launch_bounds__(256) void proj1_kernel(
    const float* __restrict__ nump, const float* __restrict__ denp,
    const float* __restrict__ w, const float* __restrict__ bi,
    float* __restrict__ out)
{
    __shared__ float swt[64 * 68];
    __shared__ float srow[64 * 68];
    __shared__ float sb[64];
    const int t = threadIdx.x;
    const int row0 = blockIdx.x * 64;
    const int bb  = row0 / 9216;
    const int rb0 = row0 - bb * 9216;

#pragma unroll
    for (int j = 0; j < 4; ++j) {          // stage w_out transposed
        const int s = t + j * 256;
        const int c = s >> 4, k4 = s & 15;
        const float4 wv = *(const float4*)(w + c * 64 + k4 * 4);
        swt[(k4 * 4 + 0) * 68 + c] = wv.x;
        swt[(k4 * 4 + 1) * 68 + c] = wv.y;
        swt[(k4 * 4 + 2) * 68 + c] = wv.z;
        swt[(k4 * 4 + 3) * 68 + c] = wv.w;
    }
#pragma unroll
    for (int j = 0; j < 4; ++j) {          // gather 64 rows from partials
        const int s = t + j * 256;
        const int rl = s >> 4, hc = s & 15;
        const int bh = bb * 4 + (hc >> 2);
        const int c4g = hc & 3;
        const int rb = rb0 + rl;
        float sx = 0.f, sy = 0.f, sz = 0.f, sw4 = 0.f, dd = 0.f;
#pragma unroll
        for (int sc = 0; sc < NP_S; ++sc) {
            const size_t rbs = (size_t)(sc * 8 + bh) * 9216 + rb;
            const float4 v = *(const float4*)(nump + rbs * 16 + c4g * 4);
            sx += v.x; sy += v.y; sz += v.z; sw4 += v.w;
            dd += denp[rbs];
        }
        const float inv = 1.0f / dd;
        float4 ov; ov.x = sx * inv; ov.y = sy * inv; ov.z = sz * inv; ov.w = sw4 * inv;
        *(float4*)&srow[rl * 68 + hc * 4] = ov;
    }
    if (t < 64) sb[t] = bi[t];
    __syncthreads();

    const int c4 = t & 15, rg = t >> 4;
    const float4 binit = *(const float4*)&sb[c4 * 4];
    float4 acc[4];
#pragma unroll
    for (int rr = 0; rr < 4; ++rr) acc[rr] = binit;
#pragma unroll
    for (int k4 = 0; k4 < 16; ++k4) {
        const float4 wq0 = *(const float4*)&swt[(k4 * 4 + 0) * 68 + c4 * 4];
        const float4 wq1 = *(const float4*)&swt[(k4 * 4 + 1) * 68 + c4 * 4];
        const float4 wq2 = *(const float4*)&swt[(k4 * 4 + 2) * 68 + c4 * 4];
        const float4 wq3 = *(const float4*)&swt[(k4 * 4 + 3) * 68 + c4 * 4];
#pragma unroll
        for (int rr = 0; rr < 4; ++rr) {
            const float4 s4 = *(const float4*)&srow[(rg + rr * 16) * 68 + k4 * 4];
            acc[rr].x = fmaf(s4.x, wq0.x, acc[rr].x);
            acc[rr].y = fmaf(s4.x, wq0.y, acc[rr].y);
            acc[rr].z = fmaf(s4.x, wq0.z, acc[rr].z);
            acc[rr].w = fmaf(s4.x, wq0.w, acc[rr].w);
            acc[rr].x = fmaf(s4.y, wq1.x, acc[rr].x);
            acc[rr].y = fmaf(s4.y, wq1.y, acc[rr].y);
            acc[rr].z = fmaf(s4.y, wq1.z, acc[rr].z);
            acc[rr].w = fmaf(s4.y, wq1.w, acc[rr].w);
            acc[rr].x = fmaf(s4.z, wq2.x, acc[rr].x);
            acc[rr].y = fmaf(s4.z, wq2.y, acc[rr].y);
            acc[rr].z = fmaf(s4.z, wq2.z, acc[rr].z);
            acc[rr].w = fmaf(s4.z, wq2.w, acc[rr].w);
            acc[rr].x = fmaf(s4.w, wq3.x, acc[rr].x);
            acc[rr].y = fmaf(s4.w, wq3.y, acc[rr].y);
            acc[rr].z = fmaf(s4.w, wq3.z, acc[rr].z);
            acc[rr].w = fmaf(s4.w, wq3.w, acc[rr].w);
        }
    }
#pragma unroll
    for (int rr = 0; rr < 4; ++rr)
        *(float4*)(out + (size_t)(row0 + rg + rr * 16) * 64 + c4 * 4) = acc[rr];
}

extern "C" void kernel_launch(void* const* d_in, const int* in_sizes, int n_in,
                              void* d_out, int out_size, void* d_ws, size_t ws_size,
                              hipStream_t stream)
{
    const float* state = (const float*)d_in[0];
    const float* w_lk  = (const float*)d_in[1];
    const float* b_lk  = (const float*)d_in[2];
    const float* w_rk  = (const float*)d_in[3];
    const float* b_rk  = (const float*)d_in[4];
    const float* w_lv  = (const float*)d_in[5];
    const float* b_lv  = (const float*)d_in[6];
    const float* w_rv  = (const float*)d_in[7];
    const float* b_rv  = (const float*)d_in[8];
    const float* w_out = (const float*)d_in[9];
    const float* b_out = (const float*)d_in[10];
    float* out = (float*)d_out;

    float* ws = (float*)d_ws;
    float* lk   = ws;                         // head-major [bh][row][16]
    float* rk   = ws + (size_t)TENS;
    float* lv   = ws + (size_t)2 * TENS;
    float* rv   = ws + (size_t)3 * TENS;
    float* nump = ws + (size_t)4 * TENS;      // 28.3 MB partials
    float* denp = nump + (size_t)NP_S * 8 * 9216 * 16;

    proj4_kernel<<<T_ROWS / 64, 256, 0, stream>>>(
        state, w_lk, b_lk, w_rk, b_rk, w_lv, b_lv, w_rv, b_rv, lk, rk, lv, rv);
    fused_attn_kernel<<<432, 256, 0, stream>>>(lk, rk, lv, rv, nump, denp);
    proj1_kernel<<<T_ROWS / 64, 256, 0, stream>>>(nump, denp, w_out, b_out, out);
}

// Round 13
// 125.205 us; speedup vs baseline: 2.9461x; 1.0782x over previous
//
#include <hip/hip_runtime.h>

// B=2, N=96, D=64, H=4, DK=16
#define TENS   1179648   // floats per projected tensor (18432*64)
#define HM     147456    // floats per (b,h) head-major plane (9216*16)
#define T_ROWS 18432
#define NP_S   6         // a-split partial count (chunks of 16 a)

// ---------------------------------------------------------------------------
// proj4 v3 (verbatim R12): 288 blocks x 64 rows; all four matrices per block.
// ---------------------------------------------------------------------------
__global__ __launch_bounds__(256) void proj4_kernel(
    const float* __restrict__ state,
    const float* __restrict__ w0, const float* __restrict__ b0,
    const float* __restrict__ w1, const float* __restrict__ b1,
    const float* __restrict__ w2, const float* __restrict__ b2,
    const float* __restrict__ w3, const float* __restrict__ b3,
    float* __restrict__ o0, float* __restrict__ o1,
    float* __restrict__ o2, float* __restrict__ o3)
{
    __shared__ float swt[64 * 68];    // [k][c] transposed, current mat
    __shared__ float srow[64 * 68];   // [row][k], staged once
    __shared__ float sb[64];
    const int t = threadIdx.x;
    const int row0 = blockIdx.x * 64;

#pragma unroll
    for (int j = 0; j < 4; ++j) {          // stage 64 src rows once
        const int s = t + j * 256;
        const int row = s >> 4, k4 = s & 15;
        *(float4*)&srow[row * 68 + k4 * 4] =
            *(const float4*)(state + (size_t)(row0 + row) * 64 + k4 * 4);
    }
    const int b   = row0 / 9216;
    const int rb0 = row0 - b * 9216;
    const int c4 = t & 15, rg = t >> 4;
    const int h  = c4 >> 2;
    const int dq = c4 & 3;

    for (int mat = 0; mat < 4; ++mat) {
        const float* w  = (mat == 0) ? w0 : (mat == 1) ? w1 : (mat == 2) ? w2 : w3;
        const float* bi = (mat == 0) ? b0 : (mat == 1) ? b1 : (mat == 2) ? b2 : b3;
        float* o        = (mat == 0) ? o0 : (mat == 1) ? o1 : (mat == 2) ? o2 : o3;

        __syncthreads();
#pragma unroll
        for (int j = 0; j < 4; ++j) {      // stage W transposed
            const int s = t + j * 256;
            const int c = s >> 4, k4 = s & 15;
            const float4 wv = *(const float4*)(w + c * 64 + k4 * 4);
            swt[(k4 * 4 + 0) * 68 + c] = wv.x;
            swt[(k4 * 4 + 1) * 68 + c] = wv.y;
            swt[(k4 * 4 + 2) * 68 + c] = wv.z;
            swt[(k4 * 4 + 3) * 68 + c] = wv.w;
        }
        if (t < 64) sb[t] = bi[t];
        __syncthreads();

        const float4 binit = *(const float4*)&sb[c4 * 4];
        float4 acc[4];
#pragma unroll
        for (int rr = 0; rr < 4; ++rr) acc[rr] = binit;
#pragma unroll
        for (int k4 = 0; k4 < 16; ++k4) {
            const float4 wq0 = *(const float4*)&swt[(k4 * 4 + 0) * 68 + c4 * 4];
            const float4 wq1 = *(const float4*)&swt[(k4 * 4 + 1) * 68 + c4 * 4];
            const float4 wq2 = *(const float4*)&swt[(k4 * 4 + 2) * 68 + c4 * 4];
            const float4 wq3 = *(const float4*)&swt[(k4 * 4 + 3) * 68 + c4 * 4];
#pragma unroll
            for (int rr = 0; rr < 4; ++rr) {
                const float4 s4 = *(const float4*)&srow[(rg + rr * 16) * 68 + k4 * 4];
                acc[rr].x = fmaf(s4.x, wq0.x, acc[rr].x);
                acc[rr].y = fmaf(s4.x, wq0.y, acc[rr].y);
                acc[rr].z = fmaf(s4.x, wq0.z, acc[rr].z);
                acc[rr].w = fmaf(s4.x, wq0.w, acc[rr].w);
                acc[rr].x = fmaf(s4.y, wq1.x, acc[rr].x);
                acc[rr].y = fmaf(s4.y, wq1.y, acc[rr].y);
                acc[rr].z = fmaf(s4.y, wq1.z, acc[rr].z);
                acc[rr].w = fmaf(s4.y, wq1.w, acc[rr].w);
                acc[rr].x = fmaf(s4.z, wq2.x, acc[rr].x);
                acc[rr].y = fmaf(s4.z, wq2.y, acc[rr].y);
                acc[rr].z = fmaf(s4.z, wq2.z, acc[rr].z);
                acc[rr].w = fmaf(s4.z, wq2.w, acc[rr].w);
                acc[rr].x = fmaf(s4.w, wq3.x, acc[rr].x);
                acc[rr].y = fmaf(s4.w, wq3.y, acc[rr].y);
                acc[rr].z = fmaf(s4.w, wq3.z, acc[rr].z);
                acc[rr].w = fmaf(s4.w, wq3.w, acc[rr].w);
            }
        }
        float* dp = o + (size_t)(b * 4 + h) * HM + dq * 4;
#pragma unroll
        for (int rr = 0; rr < 4; ++rr)
            *(float4*)(dp + (size_t)(rb0 + rg + rr * 16) * 16) = acc[rr];
    }
}

// ---------------------------------------------------------------------------
// Fused attention v4: R10 2x2 math + R7-style register-prefetch double-
// staging (prefetch tile t+1's 8 float4/thread after the commit barrier of
// tile t; global latency hides under the 4-ai compute). 432 blocks x 256.
// ---------------------------------------------------------------------------
__global__ __launch_bounds__(256) void fused_attn_kernel(
    const float* __restrict__ lk, const float* __restrict__ rk,
    const float* __restrict__ lv, const float* __restrict__ rv,
    float* __restrict__ nump, float* __restrict__ denp)
{
    __shared__ float lk_s[2176];   // 32 x-slots * pitch 68
    __shared__ float lv_s[2176];
    __shared__ float rk_s[2560];   // 4 ai * (32 y-slots * pitch 20)
    __shared__ float rv_s[2560];

    const int t = threadIdx.x;
    const int j = blockIdx.x;            // 0..431
    const int bh = j & 7;
    const int r2 = j >> 3;               // 0..53
    const int sc = r2 % 6;
    const int tile = r2 / 6;             // 0..8
    const int xt = tile % 3, yt = tile / 3;
    const int x0 = xt * 32, y0 = yt * 32;
    const int a00 = sc * 16;
    const int xi2 = t & 15, yi2 = t >> 4;

    const float* plk = lk + (size_t)bh * HM;
    const float* prk = rk + (size_t)bh * HM;
    const float* plv = lv + (size_t)bh * HM;
    const float* prv = rv + (size_t)bh * HM;

    // staging slot decomposition (constant per thread)
    const int slot1 = t + 256;
    const int xl0 = t >> 4,     lrem0 = t & 15,     lai0 = lrem0 >> 2, lc0 = lrem0 & 3;
    const int xl1 = slot1 >> 4, lrem1 = slot1 & 15, lai1 = lrem1 >> 2, lc1 = lrem1 & 3;
    const int ar0 = t >> 7,     rrem0 = t & 127,    yl0 = rrem0 >> 2,  rc0 = rrem0 & 3;
    const int ar1 = slot1 >> 7, rrem1 = slot1 & 127, yl1 = rrem1 >> 2, rc1 = rrem1 & 3;

    const float* glk0 = plk + ((x0 + xl0) * 96 + a00 + lai0) * 16 + lc0 * 4;
    const float* glk1 = plk + ((x0 + xl1) * 96 + a00 + lai1) * 16 + lc1 * 4;
    const float* glv0 = plv + ((x0 + xl0) * 96 + a00 + lai0) * 16 + lc0 * 4;
    const float* glv1 = plv + ((x0 + xl1) * 96 + a00 + lai1) * 16 + lc1 * 4;
    const float* grk0 = prk + ((a00 + ar0) * 96 + y0 + yl0) * 16 + rc0 * 4;
    const float* grk1 = prk + ((a00 + ar1) * 96 + y0 + yl1) * 16 + rc1 * 4;
    const float* grv0 = prv + ((a00 + ar0) * 96 + y0 + yl0) * 16 + rc0 * 4;
    const float* grv1 = prv + ((a00 + ar1) * 96 + y0 + yl1) * 16 + rc1 * 4;

    const int llo0 = ((xl0 & 1) * 16 + (xl0 >> 1)) * 68 + lai0 * 16 + lc0 * 4;
    const int llo1 = ((xl1 & 1) * 16 + (xl1 >> 1)) * 68 + lai1 * 16 + lc1 * 4;
    const int rlo0 = ar0 * 640 + ((yl0 & 1) * 16 + (yl0 >> 1)) * 20 + rc0 * 4;
    const int rlo1 = ar1 * 640 + ((yl1 & 1) * 16 + (yl1 >> 1)) * 20 + rc1 * 4;

    // preload tile 0
    float4 p_lk0 = *(const float4*)glk0, p_lk1 = *(const float4*)glk1;
    float4 p_lv0 = *(const float4*)glv0, p_lv1 = *(const float4*)glv1;
    float4 p_rk0 = *(const float4*)grk0, p_rk1 = *(const float4*)grk1;
    float4 p_rv0 = *(const float4*)grv0, p_rv1 = *(const float4*)grv1;

    float4 a00v = {0.f,0.f,0.f,0.f}, a01v = a00v, a02v = a00v, a03v = a00v;
    float4 a10v = a00v, a11v = a00v, a12v = a00v, a13v = a00v;
    float4 a20v = a00v, a21v = a00v, a22v = a00v, a23v = a00v;
    float4 a30v = a00v, a31v = a00v, a32v = a00v, a33v = a00v;
    float d00 = 0.f, d01 = 0.f, d10 = 0.f, d11 = 0.f;

    for (int acx = 0; acx < 4; ++acx) {
        __syncthreads();                 // LDS free (previous tile consumed)
        *(float4*)&lk_s[llo0] = p_lk0;  *(float4*)&lk_s[llo1] = p_lk1;
        *(float4*)&lv_s[llo0] = p_lv0;  *(float4*)&lv_s[llo1] = p_lv1;
        *(float4*)&rk_s[rlo0] = p_rk0;  *(float4*)&rk_s[rlo1] = p_rk1;
        *(float4*)&rv_s[rlo0] = p_rv0;  *(float4*)&rv_s[rlo1] = p_rv1;
        __syncthreads();                 // LDS ready
        if (acx < 3) {                   // prefetch next tile under compute
            glk0 += 64;   glk1 += 64;   glv0 += 64;   glv1 += 64;
            grk0 += 6144; grk1 += 6144; grv0 += 6144; grv1 += 6144;
            p_lk0 = *(const float4*)glk0; p_lk1 = *(const float4*)glk1;
            p_lv0 = *(const float4*)glv0; p_lv1 = *(const float4*)glv1;
            p_rk0 = *(const float4*)grk0; p_rk1 = *(const float4*)grk1;
            p_rv0 = *(const float4*)grv0; p_rv1 = *(const float4*)grv1;
        }
#pragma unroll
        for (int ai = 0; ai < 4; ++ai) {
            const int lo0 = xi2 * 68 + ai * 16;
            const int lo1 = (16 + xi2) * 68 + ai * 16;
            const int ro0 = ai * 640 + yi2 * 20;
            const int ro1 = ai * 640 + (16 + yi2) * 20;
            const float4 ka0 = *(const float4*)&lk_s[lo0];
            const float4 ka1 = *(const float4*)&lk_s[lo0 + 4];
            const float4 ka2 = *(const float4*)&lk_s[lo0 + 8];
            const float4 ka3 = *(const float4*)&lk_s[lo0 + 12];
            const float4 kb0 = *(const float4*)&lk_s[lo1];
            const float4 kb1 = *(const float4*)&lk_s[lo1 + 4];
            const float4 kb2 = *(const float4*)&lk_s[lo1 + 8];
            const float4 kb3 = *(const float4*)&lk_s[lo1 + 12];
            const float4 qa0 = *(const float4*)&rk_s[ro0];
            const float4 qa1 = *(const float4*)&rk_s[ro0 + 4];
            const float4 qa2 = *(const float4*)&rk_s[ro0 + 8];
            const float4 qa3 = *(const float4*)&rk_s[ro0 + 12];
            const float4 qb0 = *(const float4*)&rk_s[ro1];
            const float4 qb1 = *(const float4*)&rk_s[ro1 + 4];
            const float4 qb2 = *(const float4*)&rk_s[ro1 + 8];
            const float4 qb3 = *(const float4*)&rk_s[ro1 + 12];

#define DOT16(A0,A1,A2,A3,B0,B1,B2,B3)                                   \
    fmaf(A3.w,B3.w, fmaf(A3.z,B3.z, fmaf(A3.y,B3.y, fmaf(A3.x,B3.x,     \
    fmaf(A2.w,B2.w, fmaf(A2.z,B2.z, fmaf(A2.y,B2.y, fmaf(A2.x,B2.x,     \
    fmaf(A1.w,B1.w, fmaf(A1.z,B1.z, fmaf(A1.y,B1.y, fmaf(A1.x,B1.x,     \
    fmaf(A0.w,B0.w, fmaf(A0.z,B0.z, fmaf(A0.y,B0.y, A0.x*B0.x)))))))))))))))
            const float s00 = DOT16(ka0,ka1,ka2,ka3, qa0,qa1,qa2,qa3);
            const float s01 = DOT16(ka0,ka1,ka2,ka3, qb0,qb1,qb2,qb3);
            const float s10 = DOT16(kb0,kb1,kb2,kb3, qa0,qa1,qa2,qa3);
            const float s11 = DOT16(kb0,kb1,kb2,kb3, qb0,qb1,qb2,qb3);
#undef DOT16
            const float p00 = __expf(s00 * 0.25f);   // 1/sqrt(16); |s| << 1
            const float p01 = __expf(s01 * 0.25f);
            const float p10 = __expf(s10 * 0.25f);
            const float p11 = __expf(s11 * 0.25f);
            d00 += p00; d01 += p01; d10 += p10; d11 += p11;

            const float4 la0 = *(const float4*)&lv_s[lo0];
            const float4 la1 = *(const float4*)&lv_s[lo0 + 4];
            const float4 la2 = *(const float4*)&lv_s[lo0 + 8];
            const float4 la3 = *(const float4*)&lv_s[lo0 + 12];
            const float4 lb0 = *(const float4*)&lv_s[lo1];
            const float4 lb1 = *(const float4*)&lv_s[lo1 + 4];
            const float4 lb2 = *(const float4*)&lv_s[lo1 + 8];
            const float4 lb3 = *(const float4*)&lv_s[lo1 + 12];
            const float4 va0 = *(const float4*)&rv_s[ro0];
            const float4 va1 = *(const float4*)&rv_s[ro0 + 4];
            const float4 va2 = *(const float4*)&rv_s[ro0 + 8];
            const float4 va3 = *(const float4*)&rv_s[ro0 + 12];
            const float4 vb0 = *(const float4*)&rv_s[ro1];
            const float4 vb1 = *(const float4*)&rv_s[ro1 + 4];
            const float4 vb2 = *(const float4*)&rv_s[ro1 + 8];
            const float4 vb3 = *(const float4*)&rv_s[ro1 + 12];

#define ACC4(AC, P, L, V)                       \
    AC.x = fmaf(P * L.x, V.x, AC.x);            \
    AC.y = fmaf(P * L.y, V.y, AC.y);            \
    AC.z = fmaf(P * L.z, V.z, AC.z);            \
    AC.w = fmaf(P * L.w, V.w, AC.w);
            ACC4(a00v, p00, la0, va0) ACC4(a01v, p00, la1, va1)
            ACC4(a02v, p00, la2, va2) ACC4(a03v, p00, la3, va3)
            ACC4(a10v, p01, la0, vb0) ACC4(a11v, p01, la1, vb1)
            ACC4(a12v, p01, la2, vb2) ACC4(a13v, p01, la3, vb3)
            ACC4(a20v, p10, lb0, va0) ACC4(a21v, p10, lb1, va1)
            ACC4(a22v, p10, lb2, va2) ACC4(a23v, p10, lb3, va3)
            ACC4(a30v, p11, lb0, vb0) ACC4(a31v, p11, lb1, vb1)
            ACC4(a32v, p11, lb2, vb2) ACC4(a33v, p11, lb3, vb3)
#undef ACC4
        }
    }

    const size_t pb = (size_t)(sc * 8 + bh) * 9216;
    const int xA = x0 + 2 * xi2, yA = y0 + 2 * yi2;
    {
        const size_t rb = pb + (size_t)xA * 96 + yA;
        float4* np = (float4*)(nump + rb * 16);
        np[0] = a00v; np[1] = a01v; np[2] = a02v; np[3] = a03v;
        denp[rb] = d00;
    }
    {
        const size_t rb = pb + (size_t)xA * 96 + yA + 1;
        float4* np = (float4*)(nump + rb * 16);
        np[0] = a10v; np[1] = a11v; np[2] = a12v; np[3] = a13v;
        denp[rb] = d01;
    }
    {
        const size_t rb = pb + (size_t)(xA + 1) * 96 + yA;
        float4* np = (float4*)(nump + rb * 16);
        np[0] = a20v; np[1] = a21v; np[2] = a22v; np[3] = a23v;
        denp[rb] = d10;
    }
    {
        const size_t rb = pb + (size_t)(xA + 1) * 96 + yA + 1;
        float4* np = (float4*)(nump + rb * 16);
        np[0] = a30v; np[1] = a31v; np[2] = a32v; np[3] = a33v;
        denp[rb] = d11;
    }
}

// ---------------------------------------------------------------------------
// proj1 v3 (verbatim R12): 288 blocks x 64 rows; gather 6 partials + GEMM.
// ---------------------------------------------------------------------------
__global__ __launch_bounds__(256) void proj1_kernel(
    const float* __restrict__ nump, const float* __restrict__ denp,
    const float* __restrict__ w, const float* __restrict__ bi,
    float* __restrict__ out)
{
    __shared__ float swt[64 * 68];
    __shared__ float srow[64 * 68];
    __shared__ float sb[64];
    const int t = threadIdx.x;
    const int row0 = blockIdx.x * 64;
    const int bb  = row0 / 9216;
    const int rb0 = row0 - bb * 9216;

#pragma unroll
    for (int j = 0; j < 4; ++j) {          // stage w_out transposed
        const int s = t + j * 256;
        const int c = s >> 4, k4 = s & 15;
        const float4 wv = *(const float4*)(w + c * 64 + k4 * 4);
        swt[(k4 * 4 + 0) * 68 + c] = wv.x;
        swt[(k4 * 4 + 1) * 68 + c] = wv.y;
        swt[(k4 * 4 + 2) * 68 + c] = wv.z;
        swt[(k4 * 4 + 3) * 68 + c] = wv.w;
    }
#pragma unroll
    for (int j = 0; j < 4; ++j) {          // gather 64 rows from partials
        const int s = t + j * 256;
        const int rl = s >> 4, hc = s & 15;
        const int bh = bb * 4 + (hc >> 2);
        const int c4g = hc & 3;
        const int rb = rb0 + rl;
        float sx = 0.f, sy = 0.f, sz = 0.f, sw4 = 0.f, dd = 0.f;
#pragma unroll
        for (int sc = 0; sc < NP_S; ++sc) {
            const size_t rbs = (size_t)(sc * 8 + bh) * 9216 + rb;
            const float4 v = *(const float4*)(nump + rbs * 16 + c4g * 4);
            sx += v.x; sy += v.y; sz += v.z; sw4 += v.w;
            dd += denp[rbs];
        }
        const float inv = 1.0f / dd;
        float4 ov; ov.x = sx * inv; ov.y = sy * inv; ov.z = sz * inv; ov.w = sw4 * inv;
        *(float4*)&srow[rl * 68 + hc * 4] = ov;
    }
    if (t < 64) sb[t] = bi[t];
    __syncthreads();

    const int c4 = t & 15, rg = t >> 4;
    const float4 binit = *(const float4*)&sb[c4 * 4];
    float4 acc[4];
#pragma unroll
    for (int rr = 0; rr < 4; ++rr) acc[rr] = binit;
#pragma unroll
    for (int k4 = 0; k4 < 16; ++k4) {
        const float4 wq0 = *(const float4*)&swt[(k4 * 4 + 0) * 68 + c4 * 4];
        const float4 wq1 = *(const float4*)&swt[(k4 * 4 + 1) * 68 + c4 * 4];
        const float4 wq2 = *(const float4*)&swt[(k4 * 4 + 2) * 68 + c4 * 4];
        const float4 wq3 = *(const float4*)&swt[(k4 * 4 + 3) * 68 + c4 * 4];
#pragma unroll
        for (int rr = 0; rr < 4; ++rr) {
            const float4 s4 = *(const float4*)&srow[(rg + rr * 16) * 68 + k4 * 4];
            acc[rr].x = fmaf(s4.x, wq0.x, acc[rr].x);
            acc[rr].y = fmaf(s4.x, wq0.y, acc[rr].y);
            acc[rr].z = fmaf(s4.x, wq0.z, acc[rr].z);
            acc[rr].w = fmaf(s4.x, wq0.w, acc[rr].w);
            acc[rr].x = fmaf(s4.y, wq1.x, acc[rr].x);
            acc[rr].y = fmaf(s4.y, wq1.y, acc[rr].y);
            acc[rr].z = fmaf(s4.y, wq1.z, acc[rr].z);
            acc[rr].w = fmaf(s4.y, wq1.w, acc[rr].w);
            acc[rr].x = fmaf(s4.z, wq2.x, acc[rr].x);
            acc[rr].y = fmaf(s4.z, wq2.y, acc[rr].y);
            acc[rr].z = fmaf(s4.z, wq2.z, acc[rr].z);
            acc[rr].w = fmaf(s4.z, wq2.w, acc[rr].w);
            acc[rr].x = fmaf(s4.w, wq3.x, acc[rr].x);
            acc[rr].y = fmaf(s4.w, wq3.y, acc[rr].y);
            acc[rr].z = fmaf(s4.w, wq3.z, acc[rr].z);
            acc[rr].w = fmaf(s4.w, wq3.w, acc[rr].w);
        }
    }
#pragma unroll
    for (int rr = 0; rr < 4; ++rr)
        *(float4*)(out + (size_t)(row0 + rg + rr * 16) * 64 + c4 * 4) = acc[rr];
}

extern "C" void kernel_launch(void* const* d_in, const int* in_sizes, int n_in,
                              void* d_out, int out_size, void* d_ws, size_t ws_size,
                              hipStream_t stream)
{
    const float* state = (const float*)d_in[0];
    const float* w_lk  = (const float*)d_in[1];
    const float* b_lk  = (const float*)d_in[2];
    const float* w_rk  = (const float*)d_in[3];
    const float* b_rk  = (const float*)d_in[4];
    const float* w_lv  = (const float*)d_in[5];
    const float* b_lv  = (const float*)d_in[6];
    const float* w_rv  = (const float*)d_in[7];
    const float* b_rv  = (const float*)d_in[8];
    const float* w_out = (const float*)d_in[9];
    const float* b_out = (const float*)d_in[10];
    float* out = (float*)d_out;

    float* ws = (float*)d_ws;
    float* lk   = ws;                         // head-major [bh][row][16]
    float* rk   = ws + (size_t)TENS;
    float* lv   = ws + (size_t)2 * TENS;
    float* rv   = ws + (size_t)3 * TENS;
    float* nump = ws + (size_t)4 * TENS;      // 28.3 MB partials
    float* denp = nump + (size_t)NP_S * 8 * 9216 * 16;

    proj4_kernel<<<T_ROWS / 64, 256, 0, stream>>>(
        state, w_lk, b_lk, w_rk, b_rk, w_lv, b_lv, w_rv, b_rv, lk, rk, lv, rv);
    fused_attn_kernel<<<432, 256, 0, stream>>>(lk, rk, lv, rv, nump, denp);
    proj1_kernel<<<T_ROWS / 64, 256, 0, stream>>>(nump, denp, w_out, b_out, out);
}